// Round 1
// baseline (401.193 us; speedup 1.0000x reference)
//
#include <hip/hip_runtime.h>

#define DIM 1024
#define BATCH 4
#define SEQ 4096
#define NH 16
#define HD 64
#define KP 256

typedef float f32x4 __attribute__((ext_vector_type(4)));
typedef _Float16 half8 __attribute__((ext_vector_type(8)));

__device__ __forceinline__ void gll16(const void* g, void* l) {
  __builtin_amdgcn_global_load_lds(
      (const __attribute__((address_space(1))) void*)g,
      (__attribute__((address_space(3))) void*)l, 16, 0, 0);
}

// ---- fp32 -> fp16 elementwise convert, 8 elems/thread, exact-fit grids ----
__global__ void k_cvt(const float* __restrict__ s, _Float16* __restrict__ d) {
  int i = (blockIdx.x * 256 + threadIdx.x) * 8;
  f32x4 a = *(const f32x4*)(s + i);
  f32x4 b = *(const f32x4*)(s + i + 4);
  half8 h;
  h[0] = a[0]; h[1] = a[1]; h[2] = a[2]; h[3] = a[3];
  h[4] = b[0]; h[5] = b[1]; h[6] = b[2]; h[7] = b[3];
  *(half8*)(d + i) = h;
}

__global__ void k_zero(float* p) { p[blockIdx.x * 256 + threadIdx.x] = 0.f; }

// xsum[b,c] = sum_n x[b,n,c]; grid (4, B, 32), 128 rows per block-z
__global__ void k_xsum(const float* __restrict__ x, float* __restrict__ xs) {
  int c = blockIdx.x * 256 + threadIdx.x;
  int b = blockIdx.y;
  int n0 = blockIdx.z * 128;
  const float* p = x + (size_t)(b * SEQ + n0) * DIM + c;
  float s = 0.f;
  #pragma unroll 8
  for (int i = 0; i < 128; i++) s += p[i * DIM];
  atomicAdd(&xs[b * DIM + c], s);
}

// Sk[b,c] = xsum[b,:]@Wk[c,:], Sv likewise. One wave per output dot.
__global__ void k_sksv(const float* __restrict__ xs, const float* __restrict__ Wk,
                       const float* __restrict__ Wv, float* __restrict__ Sk,
                       float* __restrict__ Sv) {
  int idx = blockIdx.x * 4 + (threadIdx.x >> 6);
  int lane = threadIdx.x & 63;
  int kv = idx >> 12;
  int rem = idx & 4095;
  int b = rem >> 10, c = rem & 1023;
  const float* W = (kv ? Wv : Wk) + c * DIM;
  const float* xp = xs + b * DIM;
  float a = 0.f;
  #pragma unroll
  for (int i = 0; i < 16; i++) a += xp[lane + i * 64] * W[lane + i * 64];
  for (int off = 32; off; off >>= 1) a += __shfl_down(a, off);
  if (lane == 0) (kv ? Sv : Sk)[rem] = a;
}

// Ft[d,k] = F[k,d] in fp16 (so phase-2 B-fragment reads are contiguous)
__global__ void k_ft(const float* __restrict__ F, _Float16* __restrict__ Ft) {
  int i = blockIdx.x * 256 + threadIdx.x;  // 16384
  int k = i >> 6, d = i & 63;
  Ft[d * KP + k] = (_Float16)F[i];
}

// ---- m97-style fp16 MFMA GEMM: C = A(MxKd) @ Bw(NxKd)^T ----
// MODE 0: out fp16 = acc * sb[b*DIM+col] * 0.125   (Q projection, Sk folded in)
// MODE 1: out fp32 = acc + sb[col]                 (output projection + bias)
template <int MODE>
__global__ __launch_bounds__(256) void k_gemm(const _Float16* __restrict__ A,
                                              const _Float16* __restrict__ Bw,
                                              void* __restrict__ Cout,
                                              const float* __restrict__ sb) {
  __shared__ _Float16 As[128 * 32];
  __shared__ _Float16 Bs[128 * 32];
  const int tid = threadIdx.x;
  const int w = tid >> 6, lane = tid & 63;
  const int m0 = blockIdx.x * 128, n0 = blockIdx.y * 128;
  const int q4 = lane >> 4, mm = lane & 15;
  const int wm = w & 1, wn = w >> 1;
  f32x4 acc[4][4] = {};
  const _Float16* Ag = A + (m0 + w * 32 + (lane >> 2)) * DIM + (lane & 3) * 8;
  const _Float16* Bg = Bw + (n0 + w * 32 + (lane >> 2)) * DIM + (lane & 3) * 8;
  _Float16* AsW = As + w * 1024;  // 32 rows * 32 elems per wave
  _Float16* BsW = Bs + w * 1024;
  for (int k0 = 0; k0 < DIM; k0 += 32) {
    gll16(Ag + k0, AsW);
    gll16(Ag + k0 + 16 * DIM, AsW + 512);
    gll16(Bg + k0, BsW);
    gll16(Bg + k0 + 16 * DIM, BsW + 512);
    __syncthreads();
    half8 av[4], bv[4];
    const _Float16* Ap = As + (wm * 64 + mm) * 32 + q4 * 8;
    const _Float16* Bp = Bs + (wn * 64 + mm) * 32 + q4 * 8;
    #pragma unroll
    for (int t = 0; t < 4; t++) {
      av[t] = *(const half8*)(Ap + t * 512);
      bv[t] = *(const half8*)(Bp + t * 512);
    }
    #pragma unroll
    for (int mt = 0; mt < 4; mt++)
      #pragma unroll
      for (int nt = 0; nt < 4; nt++)
        acc[mt][nt] = __builtin_amdgcn_mfma_f32_16x16x32_f16(av[mt], bv[nt], acc[mt][nt], 0, 0, 0);
    __syncthreads();
  }
  const int bIdx = m0 >> 12;
  #pragma unroll
  for (int nt = 0; nt < 4; nt++) {
    int colg = n0 + wn * 64 + nt * 16 + mm;
    float s = (MODE == 0) ? sb[bIdx * DIM + colg] * 0.125f : sb[colg];
    #pragma unroll
    for (int mt = 0; mt < 4; mt++) {
      int rowg = m0 + wm * 64 + mt * 16 + q4 * 4;
      #pragma unroll
      for (int r = 0; r < 4; r++) {
        float v = acc[mt][nt][r];
        if (MODE == 0)
          ((_Float16*)Cout)[(rowg + r) * DIM + colg] = (_Float16)(v * s);
        else
          ((float*)Cout)[(rowg + r) * DIM + colg] = v + s;
      }
    }
  }
}

// ---- fused attention: per (b,h), 64-row tile; wave = 16 rows x 256 cols ----
__global__ __launch_bounds__(256) void k_attn(const _Float16* __restrict__ Q,
                                              const _Float16* __restrict__ E,
                                              const _Float16* __restrict__ Ft,
                                              const float* __restrict__ Sv,
                                              _Float16* __restrict__ O) {
  __shared__ _Float16 Ps[4][16][264];  // +8 pad: 528B row stride -> 2-way banks
  const int tid = threadIdx.x;
  const int w = tid >> 6, lane = tid & 63;
  const int q4 = lane >> 4, mm = lane & 15;
  const int bh = blockIdx.y;
  const int b = bh >> 4, h = bh & 15;
  const int rw0 = blockIdx.x * 64 + w * 16;

  // phase 1: logits = Q_scaled @ E^T  (Sk/8 already folded into Q)
  f32x4 acc[16] = {};
  const _Float16* Qp = Q + (b * SEQ + rw0 + mm) * DIM + h * HD;
  #pragma unroll
  for (int kk = 0; kk < 2; kk++) {
    half8 a = *(const half8*)(Qp + kk * 32 + q4 * 8);
    #pragma unroll
    for (int t = 0; t < 16; t++) {
      half8 bb = *(const half8*)(E + (t * 16 + mm) * HD + kk * 32 + q4 * 8);
      acc[t] = __builtin_amdgcn_mfma_f32_16x16x32_f16(a, bb, acc[t], 0, 0, 0);
    }
  }
  // softmax over 256 cols; row r of this wave lives in the 16 lanes sharing q4
  float mx[4] = {-1e30f, -1e30f, -1e30f, -1e30f};
  #pragma unroll
  for (int t = 0; t < 16; t++)
    #pragma unroll
    for (int r = 0; r < 4; r++) mx[r] = fmaxf(mx[r], acc[t][r]);
  #pragma unroll
  for (int r = 0; r < 4; r++)
    for (int msk = 1; msk < 16; msk <<= 1) mx[r] = fmaxf(mx[r], __shfl_xor(mx[r], msk));
  float sm[4] = {0.f, 0.f, 0.f, 0.f};
  #pragma unroll
  for (int t = 0; t < 16; t++)
    #pragma unroll
    for (int r = 0; r < 4; r++) {
      float p = __expf(acc[t][r] - mx[r]);
      acc[t][r] = p;
      sm[r] += p;
    }
  #pragma unroll
  for (int r = 0; r < 4; r++) {
    for (int msk = 1; msk < 16; msk <<= 1) sm[r] += __shfl_xor(sm[r], msk);
    sm[r] = 1.f / sm[r];
  }
  // C-layout -> A-layout via LDS
  #pragma unroll
  for (int t = 0; t < 16; t++)
    #pragma unroll
    for (int r = 0; r < 4; r++)
      Ps[w][q4 * 4 + r][t * 16 + mm] = (_Float16)(acc[t][r] * sm[r]);
  __syncthreads();

  // phase 2: out = P @ F, then * Sv
  f32x4 acc2[4] = {};
  #pragma unroll
  for (int kk = 0; kk < 8; kk++) {
    half8 a = *(const half8*)&Ps[w][mm][kk * 32 + q4 * 8];
    #pragma unroll
    for (int nt = 0; nt < 4; nt++) {
      half8 bb = *(const half8*)(Ft + (nt * 16 + mm) * KP + kk * 32 + q4 * 8);
      acc2[nt] = __builtin_amdgcn_mfma_f32_16x16x32_f16(a, bb, acc2[nt], 0, 0, 0);
    }
  }
  #pragma unroll
  for (int nt = 0; nt < 4; nt++) {
    float sv = Sv[b * DIM + h * HD + nt * 16 + mm];
    #pragma unroll
    for (int r = 0; r < 4; r++)
      O[(b * SEQ + rw0 + q4 * 4 + r) * DIM + h * HD + nt * 16 + mm] =
          (_Float16)(acc2[nt][r] * sv);
  }
}

extern "C" void kernel_launch(void* const* d_in, const int* in_sizes, int n_in,
                              void* d_out, int out_size, void* d_ws, size_t ws_size,
                              hipStream_t stream) {
  (void)in_sizes; (void)n_in; (void)out_size; (void)ws_size;
  const float* x  = (const float*)d_in[0];
  const float* Wq = (const float*)d_in[1];
  const float* Wk = (const float*)d_in[2];
  const float* Wv = (const float*)d_in[3];
  const float* E  = (const float*)d_in[4];
  const float* F  = (const float*)d_in[5];
  const float* Wo = (const float*)d_in[6];
  const float* bo = (const float*)d_in[7];
  char* ws = (char*)d_ws;
  // workspace layout (68.1 MB total); O_h aliases x_h (x_h dead after Q GEMM)
  _Float16* x_h  = (_Float16*)(ws);
  _Float16* O_h  = (_Float16*)(ws);
  _Float16* Q_h  = (_Float16*)(ws + 33554432);
  _Float16* Wq_h = (_Float16*)(ws + 67108864);
  _Float16* Wo_h = (_Float16*)(ws + 69206016);
  _Float16* E_h  = (_Float16*)(ws + 71303168);
  _Float16* Ft_h = (_Float16*)(ws + 71335936);
  float* xsum    = (float*)(ws + 71368704);
  float* Sk      = (float*)(ws + 71385088);
  float* Sv      = (float*)(ws + 71401472);
  float* out     = (float*)d_out;

  k_zero<<<16, 256, 0, stream>>>(xsum);
  k_xsum<<<dim3(4, BATCH, 32), 256, 0, stream>>>(x, xsum);
  k_cvt<<<8192, 256, 0, stream>>>(x, x_h);
  k_cvt<<<512, 256, 0, stream>>>(Wq, Wq_h);
  k_cvt<<<512, 256, 0, stream>>>(Wo, Wo_h);
  k_cvt<<<8, 256, 0, stream>>>(E, E_h);
  k_ft<<<64, 256, 0, stream>>>(F, Ft_h);
  k_sksv<<<2048, 256, 0, stream>>>(xsum, Wk, Wv, Sk, Sv);
  k_gemm<0><<<dim3(128, 8), 256, 0, stream>>>(x_h, Wq_h, (void*)Q_h, Sk);
  k_attn<<<dim3(64, 64), 256, 0, stream>>>(Q_h, E_h, Ft_h, Sv, O_h);
  k_gemm<1><<<dim3(128, 8), 256, 0, stream>>>(O_h, Wo_h, (void*)out, bo);
}

// Round 2
// 315.678 us; speedup vs baseline: 1.2709x; 1.2709x over previous
//
#include <hip/hip_runtime.h>

#define DIM 1024
#define BATCH 4
#define SEQ 4096
#define NH 16
#define HD 64
#define KP 256

typedef float f32x4 __attribute__((ext_vector_type(4)));
typedef _Float16 half8 __attribute__((ext_vector_type(8)));

__device__ __forceinline__ void gll16(const void* g, void* l) {
  __builtin_amdgcn_global_load_lds(
      (const __attribute__((address_space(1))) void*)g,
      (__attribute__((address_space(3))) void*)l, 16, 0, 0);
}

// ---- fp32 -> fp16 elementwise convert, 8 elems/thread, exact-fit grids ----
__global__ void k_cvt(const float* __restrict__ s, _Float16* __restrict__ d) {
  int i = (blockIdx.x * 256 + threadIdx.x) * 8;
  f32x4 a = *(const f32x4*)(s + i);
  f32x4 b = *(const f32x4*)(s + i + 4);
  half8 h;
  h[0] = a[0]; h[1] = a[1]; h[2] = a[2]; h[3] = a[3];
  h[4] = b[0]; h[5] = b[1]; h[6] = b[2]; h[7] = b[3];
  *(half8*)(d + i) = h;
}

__global__ void k_zero(float* p) { p[blockIdx.x * 256 + threadIdx.x] = 0.f; }

// xsum[b,c] = sum_n x[b,n,c]; grid (4, B, 32), 128 rows per block-z
__global__ void k_xsum(const float* __restrict__ x, float* __restrict__ xs) {
  int c = blockIdx.x * 256 + threadIdx.x;
  int b = blockIdx.y;
  int n0 = blockIdx.z * 128;
  const float* p = x + (size_t)(b * SEQ + n0) * DIM + c;
  float s = 0.f;
  #pragma unroll 8
  for (int i = 0; i < 128; i++) s += p[i * DIM];
  atomicAdd(&xs[b * DIM + c], s);
}

// Sk[b,c] = xsum[b,:]@Wk[c,:], Sv likewise. One wave per output dot.
__global__ void k_sksv(const float* __restrict__ xs, const float* __restrict__ Wk,
                       const float* __restrict__ Wv, float* __restrict__ Sk,
                       float* __restrict__ Sv) {
  int idx = blockIdx.x * 4 + (threadIdx.x >> 6);
  int lane = threadIdx.x & 63;
  int kv = idx >> 12;
  int rem = idx & 4095;
  int b = rem >> 10, c = rem & 1023;
  const float* W = (kv ? Wv : Wk) + c * DIM;
  const float* xp = xs + b * DIM;
  float a = 0.f;
  #pragma unroll
  for (int i = 0; i < 16; i++) a += xp[lane + i * 64] * W[lane + i * 64];
  for (int off = 32; off; off >>= 1) a += __shfl_down(a, off);
  if (lane == 0) (kv ? Sv : Sk)[rem] = a;
}

// Ftp[d][col'] = F[k][d], col' = (k%16)*16 + k/16 (k-permuted transpose, fp16).
// Phase-2 feeds A (P) and B (Ftp) in the SAME permuted k-order -> dot invariant.
__global__ void k_ft(const float* __restrict__ F, _Float16* __restrict__ Ft) {
  int i = blockIdx.x * 256 + threadIdx.x;  // 16384
  int k = i >> 6, d = i & 63;
  Ft[d * KP + (k & 15) * 16 + (k >> 4)] = (_Float16)F[i];
}

// ---- m97-style fp16 MFMA GEMM: C = A(MxKd) @ Bw(NxKd)^T ----
// MODE 0: out fp16 = acc * sb[b*DIM+col] * 0.125 * log2e  (Q proj, Sk+log2e folded)
// MODE 1: out fp32 = acc + sb[col]                        (output proj + bias)
template <int MODE>
__global__ __launch_bounds__(256) void k_gemm(const _Float16* __restrict__ A,
                                              const _Float16* __restrict__ Bw,
                                              void* __restrict__ Cout,
                                              const float* __restrict__ sb) {
  __shared__ _Float16 As[128 * 32];
  __shared__ _Float16 Bs[128 * 32];
  const int tid = threadIdx.x;
  const int w = tid >> 6, lane = tid & 63;
  const int m0 = blockIdx.x * 128, n0 = blockIdx.y * 128;
  const int q4 = lane >> 4, mm = lane & 15;
  const int wm = w & 1, wn = w >> 1;
  f32x4 acc[4][4] = {};
  const _Float16* Ag = A + (m0 + w * 32 + (lane >> 2)) * DIM + (lane & 3) * 8;
  const _Float16* Bg = Bw + (n0 + w * 32 + (lane >> 2)) * DIM + (lane & 3) * 8;
  _Float16* AsW = As + w * 1024;  // 32 rows * 32 elems per wave
  _Float16* BsW = Bs + w * 1024;
  for (int k0 = 0; k0 < DIM; k0 += 32) {
    gll16(Ag + k0, AsW);
    gll16(Ag + k0 + 16 * DIM, AsW + 512);
    gll16(Bg + k0, BsW);
    gll16(Bg + k0 + 16 * DIM, BsW + 512);
    __syncthreads();
    half8 av[4], bv[4];
    const _Float16* Ap = As + (wm * 64 + mm) * 32 + q4 * 8;
    const _Float16* Bp = Bs + (wn * 64 + mm) * 32 + q4 * 8;
    #pragma unroll
    for (int t = 0; t < 4; t++) {
      av[t] = *(const half8*)(Ap + t * 512);
      bv[t] = *(const half8*)(Bp + t * 512);
    }
    #pragma unroll
    for (int mt = 0; mt < 4; mt++)
      #pragma unroll
      for (int nt = 0; nt < 4; nt++)
        acc[mt][nt] = __builtin_amdgcn_mfma_f32_16x16x32_f16(av[mt], bv[nt], acc[mt][nt], 0, 0, 0);
    __syncthreads();
  }
  const int bIdx = m0 >> 12;
  #pragma unroll
  for (int nt = 0; nt < 4; nt++) {
    int colg = n0 + wn * 64 + nt * 16 + mm;
    float s = (MODE == 0) ? sb[bIdx * DIM + colg] * (0.125f * 1.44269504088896f)
                          : sb[colg];
    #pragma unroll
    for (int mt = 0; mt < 4; mt++) {
      int rowg = m0 + wm * 64 + mt * 16 + q4 * 4;
      #pragma unroll
      for (int r = 0; r < 4; r++) {
        float v = acc[mt][nt][r];
        if (MODE == 0)
          ((_Float16*)Cout)[(rowg + r) * DIM + colg] = (_Float16)(v * s);
        else
          ((float*)Cout)[(rowg + r) * DIM + colg] = v + s;
      }
    }
  }
}

// ---- fused attention v2: all E/F fragments in registers, 16 row-tiles/wave ----
// grid (4, 64): block = (b,h, quarter of rows); wave = 16 rows/tile, 16 tiles.
// No __syncthreads: each wave owns its Ps slice (in-wave DS ordering suffices).
__global__ __launch_bounds__(256, 1) void k_attn(const _Float16* __restrict__ Q,
                                                 const _Float16* __restrict__ E,
                                                 const _Float16* __restrict__ Ftp,
                                                 const float* __restrict__ Sv,
                                                 _Float16* __restrict__ O) {
  __shared__ _Float16 Ps[4][16][264];  // per-wave 16x256 P tile, +8 pad
  const int tid = threadIdx.x;
  const int w = tid >> 6, lane = tid & 63;
  const int q4 = lane >> 4, mm = lane & 15;
  const int bh = blockIdx.y;
  const int b = bh >> 4, h = bh & 15;
  const int row_base = blockIdx.x * 1024 + w * 256;

  // cold fragments, loaded once, reused by all 16 tiles
  half8 ef[16][2];  // E  B-frags: E[(t*16+mm)][kk*32+q4*8 ..]
  #pragma unroll
  for (int t = 0; t < 16; t++)
    #pragma unroll
    for (int kk = 0; kk < 2; kk++)
      ef[t][kk] = *(const half8*)(E + (t * 16 + mm) * HD + kk * 32 + q4 * 8);
  half8 ff[4][8];  // Ftp B-frags (k-permuted): Ftp[(nt*16+mm)][kk*32+q4*8 ..]
  #pragma unroll
  for (int nt = 0; nt < 4; nt++)
    #pragma unroll
    for (int kk = 0; kk < 8; kk++)
      ff[nt][kk] = *(const half8*)(Ftp + (nt * 16 + mm) * KP + kk * 32 + q4 * 8);
  float sv[4];
  #pragma unroll
  for (int nt = 0; nt < 4; nt++) sv[nt] = Sv[b * DIM + h * HD + nt * 16 + mm];

  const _Float16* Qbase = Q + ((size_t)(b * SEQ + row_base + mm)) * DIM + h * HD + q4 * 8;
  half8 qa0 = *(const half8*)(Qbase);
  half8 qa1 = *(const half8*)(Qbase + 32);

  for (int tile = 0; tile < 16; tile++) {
    // phase 1: logits (already scaled by Sk/8*log2e upstream)
    f32x4 acc[16] = {};
    #pragma unroll
    for (int t = 0; t < 16; t++)
      acc[t] = __builtin_amdgcn_mfma_f32_16x16x32_f16(qa0, ef[t][0], acc[t], 0, 0, 0);
    #pragma unroll
    for (int t = 0; t < 16; t++)
      acc[t] = __builtin_amdgcn_mfma_f32_16x16x32_f16(qa1, ef[t][1], acc[t], 0, 0, 0);
    // prefetch next tile's Q while softmax runs
    half8 qn0, qn1;
    if (tile < 15) {
      const _Float16* Qn = Qbase + (size_t)(tile + 1) * 16 * DIM;
      qn0 = *(const half8*)(Qn);
      qn1 = *(const half8*)(Qn + 32);
    }
    // softmax over 256 cols (base-2 domain); row r lives in 16 lanes sharing q4
    float mx[4] = {-1e30f, -1e30f, -1e30f, -1e30f};
    #pragma unroll
    for (int t = 0; t < 16; t++)
      #pragma unroll
      for (int r = 0; r < 4; r++) mx[r] = fmaxf(mx[r], acc[t][r]);
    #pragma unroll
    for (int r = 0; r < 4; r++)
      for (int msk = 1; msk < 16; msk <<= 1) mx[r] = fmaxf(mx[r], __shfl_xor(mx[r], msk));
    float sm[4] = {0.f, 0.f, 0.f, 0.f};
    #pragma unroll
    for (int t = 0; t < 16; t++)
      #pragma unroll
      for (int r = 0; r < 4; r++) {
        float p = __builtin_amdgcn_exp2f(acc[t][r] - mx[r]);
        acc[t][r] = p;
        sm[r] += p;
      }
    #pragma unroll
    for (int r = 0; r < 4; r++) {
      for (int msk = 1; msk < 16; msk <<= 1) sm[r] += __shfl_xor(sm[r], msk);
      sm[r] = 1.f / sm[r];
    }
    // P -> LDS in permuted-col layout: (row, k=t*16+mm) -> col' = mm*16 + t
    // lane's 16 t-values are contiguous -> 2x ds_write_b128 per row r
    #pragma unroll
    for (int r = 0; r < 4; r++) {
      half8 h0, h1;
      #pragma unroll
      for (int t = 0; t < 8; t++) h0[t] = (_Float16)(acc[t][r] * sm[r]);
      #pragma unroll
      for (int t = 0; t < 8; t++) h1[t] = (_Float16)(acc[t + 8][r] * sm[r]);
      *(half8*)&Ps[w][q4 * 4 + r][mm * 16] = h0;
      *(half8*)&Ps[w][q4 * 4 + r][mm * 16 + 8] = h1;
    }
    // phase 2: out = P @ F (both operands in permuted k-order), then * Sv
    f32x4 acc2[4] = {};
    #pragma unroll
    for (int kk = 0; kk < 8; kk++) {
      half8 pa = *(const half8*)&Ps[w][mm][kk * 32 + q4 * 8];
      #pragma unroll
      for (int nt = 0; nt < 4; nt++)
        acc2[nt] = __builtin_amdgcn_mfma_f32_16x16x32_f16(pa, ff[nt][kk], acc2[nt], 0, 0, 0);
    }
    const int rw0 = row_base + tile * 16;
    #pragma unroll
    for (int nt = 0; nt < 4; nt++)
      #pragma unroll
      for (int r = 0; r < 4; r++)
        O[(size_t)(b * SEQ + rw0 + q4 * 4 + r) * DIM + h * HD + nt * 16 + mm] =
            (_Float16)(acc2[nt][r] * sv[nt]);
    qa0 = qn0;
    qa1 = qn1;
  }
}

extern "C" void kernel_launch(void* const* d_in, const int* in_sizes, int n_in,
                              void* d_out, int out_size, void* d_ws, size_t ws_size,
                              hipStream_t stream) {
  (void)in_sizes; (void)n_in; (void)out_size; (void)ws_size;
  const float* x  = (const float*)d_in[0];
  const float* Wq = (const float*)d_in[1];
  const float* Wk = (const float*)d_in[2];
  const float* Wv = (const float*)d_in[3];
  const float* E  = (const float*)d_in[4];
  const float* F  = (const float*)d_in[5];
  const float* Wo = (const float*)d_in[6];
  const float* bo = (const float*)d_in[7];
  char* ws = (char*)d_ws;
  // workspace layout (68.1 MB total); O_h aliases x_h (x_h dead after Q GEMM)
  _Float16* x_h  = (_Float16*)(ws);
  _Float16* O_h  = (_Float16*)(ws);
  _Float16* Q_h  = (_Float16*)(ws + 33554432);
  _Float16* Wq_h = (_Float16*)(ws + 67108864);
  _Float16* Wo_h = (_Float16*)(ws + 69206016);
  _Float16* E_h  = (_Float16*)(ws + 71303168);
  _Float16* Ft_h = (_Float16*)(ws + 71335936);
  float* xsum    = (float*)(ws + 71368704);
  float* Sk      = (float*)(ws + 71385088);
  float* Sv      = (float*)(ws + 71401472);
  float* out     = (float*)d_out;

  k_zero<<<16, 256, 0, stream>>>(xsum);
  k_xsum<<<dim3(4, BATCH, 32), 256, 0, stream>>>(x, xsum);
  k_cvt<<<8192, 256, 0, stream>>>(x, x_h);
  k_cvt<<<512, 256, 0, stream>>>(Wq, Wq_h);
  k_cvt<<<512, 256, 0, stream>>>(Wo, Wo_h);
  k_cvt<<<8, 256, 0, stream>>>(E, E_h);
  k_ft<<<64, 256, 0, stream>>>(F, Ft_h);
  k_sksv<<<2048, 256, 0, stream>>>(xsum, Wk, Wv, Sk, Sv);
  k_gemm<0><<<dim3(128, 8), 256, 0, stream>>>(x_h, Wq_h, (void*)Q_h, Sk);
  k_attn<<<dim3(4, 64), 256, 0, stream>>>(Q_h, E_h, Ft_h, Sv, O_h);
  k_gemm<1><<<dim3(128, 8), 256, 0, stream>>>(O_h, Wo_h, (void*)out, bo);
}